// Round 17
// baseline (146.017 us; speedup 1.0000x reference)
//
#include <hip/hip_runtime.h>
#include <math.h>

// HeadAttention B=4, S=4096, D=1024, DK=DV=64, fp32 in/out, causal.
// Round 17: proj reverted to the ROUND-1 fp32 VALU structure -- the fastest
// proj ever measured in this session (~65us) and ~95% of the scalar-FMA
// roofline (6.44 GFLOP / 103 TF = 62us). Ten MFMA-proj hypotheses all
// plateaued at 77-85us: the MFMA floor (8us) is unreachable behind a
// memory/sync pathology, while the VALU version's ~1000cy compute phases
// bury all latency. Upgrades vs R1: (1) epilogue emits hi/lo f16 + vt
// (exact fp32 -> split, attn unchanged, wsplit dropped); (2) inner loop
// via __builtin_elementwise_fma on f32x4 so clang can emit v_pk_fma_f32
// (packed fp32: floor halves to ~31us if emitted); (3) next tile's loads
// issued right after the staging barrier (fly under compute).
// attn / combine unchanged.

#define SEQ 4096
#define DIM 1024
#define HD  64
#define NB  4
#define NSPLIT 4

typedef __attribute__((ext_vector_type(4))) float    f32x4;
typedef __attribute__((ext_vector_type(8))) _Float16 f16x8;
typedef __attribute__((ext_vector_type(4))) _Float16 f16x4;

#define MFMA16 __builtin_amdgcn_mfma_f32_16x16x32_f16

// swizzled offset into a [row][64] f16 LDS tile (attn): XOR 16B-chunk with row&7
__device__ __forceinline__ int SW(int row, int k) {
  return row * 64 + (k ^ ((row & 7) << 3));
}

// ---------- projection: fp32 VALU GEMM (R1 structure) ----------------------
// grid (256, 3), 256 threads. Y[64,64] tile = X[64,1024] @ W[1024,64].
// 32 K-tiles of 32: load tile to regs -> sync -> stage LDS (A transposed
// [kk][row], B [kk][col], shared AB buffer rows 0-31/32-63) -> sync ->
// issue next tile's loads -> 32x {2 LDS f32x4 reads, 4 packed-fma groups}.
// Epilogue: which<2 -> hi/lo f16 split (q scaled by log2e/8); which==2 ->
// in-place LDS transpose -> vt[b][col][pos] f16.
__global__ __launch_bounds__(256) void proj_kernel(
    const float* __restrict__ Xq, const float* __restrict__ Xk,
    const float* __restrict__ Xv,
    const float* __restrict__ Wq, const float* __restrict__ Wk,
    const float* __restrict__ Wv,
    _Float16* __restrict__ qh, _Float16* __restrict__ ql,
    _Float16* __restrict__ kh, _Float16* __restrict__ kl,
    _Float16* __restrict__ vt)
{
  __shared__ __attribute__((aligned(16))) float AB[64][68];  // 17.4 KB

  const int which = blockIdx.y;
  const float* __restrict__ X = (which == 0) ? Xq : (which == 1) ? Xk : Xv;
  const float* __restrict__ W = (which == 0) ? Wq : (which == 1) ? Wk : Wv;

  const int t = threadIdx.x;
  const int bm = blockIdx.x * 64;
  const int r0 = (t >> 4) * 4;    // 16x16 thread grid, 4x4 micro-tile
  const int c0 = (t & 15) * 4;

  const int arow = t >> 2;        // A: 64 rows x 32 k, 2 f32x4/thread
  const int ac0  = (t & 3) * 8;
  const int wrow = t >> 3;        // W: 32 k x 64 cols, 2 f32x4/thread
  const int wc0  = (t & 7) * 8;
  const float* gA = X + (size_t)(bm + arow) * DIM + ac0;
  const float* gB = W + (size_t)wrow * HD + wc0;

  f32x4 acc[4] = {{0,0,0,0},{0,0,0,0},{0,0,0,0},{0,0,0,0}};  // acc[i] over j
  f32x4 a0, a1, b0, b1;

  auto loadT = [&](int kt) {
    const float* ap = gA + kt * 32;
    a0 = *(const f32x4*)(ap);
    a1 = *(const f32x4*)(ap + 4);
    const float* bp = gB + (size_t)kt * 32 * HD;
    b0 = *(const f32x4*)(bp);
    b1 = *(const f32x4*)(bp + 4);
  };

  loadT(0);
#pragma unroll 1
  for (int kt = 0; kt < DIM / 32; ++kt) {
    __syncthreads();              // all waves done reading previous tile
#pragma unroll
    for (int u = 0; u < 4; ++u) AB[ac0 + u][arow]     = a0[u];
#pragma unroll
    for (int u = 0; u < 4; ++u) AB[ac0 + 4 + u][arow] = a1[u];
    *(f32x4*)&AB[32 + wrow][wc0]     = b0;
    *(f32x4*)&AB[32 + wrow][wc0 + 4] = b1;
    __syncthreads();              // staged
    if (kt + 1 < DIM / 32) loadT(kt + 1);   // flies under compute
#pragma unroll
    for (int kk = 0; kk < 32; ++kk) {
      f32x4 a  = *(const f32x4*)&AB[kk][r0];
      f32x4 wv = *(const f32x4*)&AB[32 + kk][c0];
#pragma unroll
      for (int i = 0; i < 4; ++i) {
        const f32x4 as = {a[i], a[i], a[i], a[i]};
        acc[i] = __builtin_elementwise_fma(as, wv, acc[i]);
      }
    }
  }

  // ---- epilogue
  if (which < 2) {
    const float scale = (which == 0) ? 0.18033688011112042f : 1.0f; // log2e/8
    _Float16* oh = (which == 0) ? qh : kh;
    _Float16* ol = (which == 0) ? ql : kl;
#pragma unroll
    for (int i = 0; i < 4; ++i) {
      f16x4 hv, lv;
#pragma unroll
      for (int j = 0; j < 4; ++j) {
        const float y = acc[i][j] * scale;
        const _Float16 h = (_Float16)y;
        hv[j] = h;
        lv[j] = (_Float16)(y - (float)h);
      }
      const size_t idx = (size_t)(bm + r0 + i) * HD + c0;
      *(f16x4*)&oh[idx] = hv;
      *(f16x4*)&ol[idx] = lv;
    }
  } else {
    // V: transpose through AB (reused), emit vt[b][col][pos] f16
    __syncthreads();              // all compute reads of AB done
#pragma unroll
    for (int i = 0; i < 4; ++i)
#pragma unroll
      for (int j = 0; j < 4; ++j) AB[r0 + i][c0 + j] = acc[i][j];
    __syncthreads();
    const int col = t >> 2;         // 0..63
    const int pc  = (t & 3) * 16;   // pos chunk
    const int batch = bm >> 12;
    const int pos0  = (bm & 4095) + pc;
    f16x8 o0, o1;
#pragma unroll
    for (int p = 0; p < 8; ++p) {
      o0[p] = (_Float16)AB[pc + p][col];
      o1[p] = (_Float16)AB[pc + 8 + p][col];
    }
    _Float16* vb = vt + ((size_t)batch * HD + col) * SEQ + pos0;
    *(f16x8*)(vb)     = o0;
    *(f16x8*)(vb + 8) = o1;
  }
}

// ---------- flash attention, fp16x3 QK + f16 PV, split-4 partials ----------
// grid (128, 4): x -> pair p=x>>2 (q-blocks p and 63-p), parity s=x&3.
__global__ __launch_bounds__(256) void attn_kernel(
    const _Float16* __restrict__ qh, const _Float16* __restrict__ ql,
    const _Float16* __restrict__ kh, const _Float16* __restrict__ kl,
    const _Float16* __restrict__ vt,
    _Float16* __restrict__ opart, float* __restrict__ mlp)
{
  __shared__ __attribute__((aligned(16))) _Float16 Ksh[64 * 64];
  __shared__ __attribute__((aligned(16))) _Float16 Ksl[64 * 64];
  __shared__ __attribute__((aligned(16))) _Float16 Vs [64 * 64];
  __shared__ __attribute__((aligned(16))) _Float16 Pt [64 * 64];

  const int t = threadIdx.x, lane = t & 63, w = t >> 6;
  const int b = blockIdx.y;
  const int p = blockIdx.x >> 2, s = blockIdx.x & 3;
  const size_t bS = (size_t)b * SEQ;

  for (int sel = 0; sel < 2; ++sel) {
    const int qb = sel ? (63 - p) : p;
    const int qrow0 = qb * 64 + w * 16;
    const int nt = (qb >= s) ? ((qb - s) >> 2) + 1 : 0;  // kv tiles ≡ s mod 4

    float m[4] = {-INFINITY, -INFINITY, -INFINITY, -INFINITY};
    float lsum[4] = {0.f, 0.f, 0.f, 0.f};
    f32x4 o[4] = {{0,0,0,0},{0,0,0,0},{0,0,0,0},{0,0,0,0}};

    if (nt > 0) {
      const _Float16* qhp = qh + (bS + qrow0 + (lane & 15)) * HD + ((lane >> 4) * 8);
      const _Float16* qlp = ql + (bS + qrow0 + (lane & 15)) * HD + ((lane >> 4) * 8);
      f16x8 qhf[2], qlf[2];
      qhf[0] = *(const f16x8*)(qhp);      qhf[1] = *(const f16x8*)(qhp + 32);
      qlf[0] = *(const f16x8*)(qlp);      qlf[1] = *(const f16x8*)(qlp + 32);

      for (int i = 0; i < nt; ++i) {
        const int kt = s + 4 * i;
        const int j0 = kt * 64;

        __syncthreads();  // previous tile's LDS reads complete
#pragma unroll
        for (int c = 0; c < 2; ++c) {
          const int lin = t + 256 * c;
          const int row = lin >> 3, d8 = (lin & 7) * 8;
          const int dst = SW(row, d8);
          *(f16x8*)&Ksh[dst] = *(const f16x8*)&kh[(bS + j0 + row) * HD + d8];
          *(f16x8*)&Ksl[dst] = *(const f16x8*)&kl[(bS + j0 + row) * HD + d8];
          *(f16x8*)&Vs[dst]  = *(const f16x8*)&vt[((size_t)b * HD + row) * SEQ + j0 + d8];
        }
        __syncthreads();

        // ---- QK^T: fp16x3
        f32x4 sacc[4] = {{0,0,0,0},{0,0,0,0},{0,0,0,0},{0,0,0,0}};
#pragma unroll
        for (int kk = 0; kk < 2; ++kk)
#pragma unroll
          for (int kt4 = 0; kt4 < 4; ++kt4) {
            const int ba = SW(kt4 * 16 + (lane & 15), kk * 32 + (lane >> 4) * 8);
            f16x8 bh = *(const f16x8*)&Ksh[ba];
            f16x8 bl = *(const f16x8*)&Ksl[ba];
            sacc[kt4] = MFMA16(qhf[kk], bh, sacc[kt4], 0, 0, 0);
            sacc[kt4] = MFMA16(qlf[kk], bh, sacc[kt4], 0, 0, 0);
            sacc[kt4] = MFMA16(qhf[kk], bl, sacc[kt4], 0, 0, 0);
          }

        // ---- causal mask on the diagonal tile
        if (kt == qb) {
#pragma unroll
          for (int kt4 = 0; kt4 < 4; ++kt4) {
            const int key = j0 + kt4 * 16 + (lane & 15);
#pragma unroll
            for (int r = 0; r < 4; ++r)
              if (key > qrow0 + (lane >> 4) * 4 + r) sacc[kt4][r] = -INFINITY;
          }
        }

        // ---- online softmax (exp2 domain), P -> LDS f16
        float alf[4];
#pragma unroll
        for (int r = 0; r < 4; ++r) {
          float mx = fmaxf(fmaxf(sacc[0][r], sacc[1][r]),
                           fmaxf(sacc[2][r], sacc[3][r]));
          mx = fmaxf(mx, __shfl_xor(mx, 1));
          mx = fmaxf(mx, __shfl_xor(mx, 2));
          mx = fmaxf(mx, __shfl_xor(mx, 4));
          mx = fmaxf(mx, __shfl_xor(mx, 8));
          const float mn = fmaxf(m[r], mx);
          const float al = exp2f(m[r] - mn);
          const int prow = w * 16 + (lane >> 4) * 4 + r;
          float ps = 0.f;
#pragma unroll
          for (int kt4 = 0; kt4 < 4; ++kt4) {
            const _Float16 ph = (_Float16)exp2f(sacc[kt4][r] - mn);
            ps += (float)ph;
            Pt[SW(prow, kt4 * 16 + (lane & 15))] = ph;
          }
          ps += __shfl_xor(ps, 1);
          ps += __shfl_xor(ps, 2);
          ps += __shfl_xor(ps, 4);
          ps += __shfl_xor(ps, 8);
          lsum[r] = lsum[r] * al + ps;
          m[r] = mn;
          alf[r] = al;
        }
        const f32x4 av = {alf[0], alf[1], alf[2], alf[3]};
#pragma unroll
        for (int ct = 0; ct < 4; ++ct) o[ct] *= av;

        // ---- PV (per-wave Pt region)
#pragma unroll
        for (int kk = 0; kk < 2; ++kk) {
          f16x8 pa = *(const f16x8*)&Pt[SW(w * 16 + (lane & 15),
                                           kk * 32 + (lane >> 4) * 8)];
#pragma unroll
          for (int ct = 0; ct < 4; ++ct) {
            f16x8 vb = *(const f16x8*)&Vs[SW(ct * 16 + (lane & 15),
                                             kk * 32 + (lane >> 4) * 8)];
            o[ct] = MFMA16(pa, vb, o[ct], 0, 0, 0);
          }
        }
      }
    }

    // ---- write partials: normalized o (f16) + (m, l) f32
    f32x4 invv;
#pragma unroll
    for (int r = 0; r < 4; ++r) invv[r] = (nt > 0) ? 1.0f / lsum[r] : 0.0f;
    const size_t ridx0 = (size_t)(b * NSPLIT + s) * SEQ + qrow0 + (lane >> 4) * 4;
#pragma unroll
    for (int ct = 0; ct < 4; ++ct)
#pragma unroll
      for (int r = 0; r < 4; ++r)
        opart[(ridx0 + r) * HD + ct * 16 + (lane & 15)] =
            (_Float16)(o[ct][r] * invv[r]);
    if ((lane & 15) == 0) {
#pragma unroll
      for (int r = 0; r < 4; ++r) {
        mlp[(ridx0 + r) * 2]     = m[r];
        mlp[(ridx0 + r) * 2 + 1] = lsum[r];
      }
    }
  }
}

// ---------- combine the 4 kv-parity partials -------------------------------
__global__ __launch_bounds__(256) void combine_kernel(
    const _Float16* __restrict__ opart, const float* __restrict__ mlp,
    float* __restrict__ out)
{
  const int g = blockIdx.x * 256 + threadIdx.x;   // 262144
  const int row = g >> 4;
  const int cq = (g & 15) * 4;
  const int b = row >> 12, pos = row & 4095;

  float mv[4], lv[4], msx = -INFINITY;
#pragma unroll
  for (int s = 0; s < 4; ++s) {
    const size_t ri = (size_t)(b * NSPLIT + s) * SEQ + pos;
    mv[s] = mlp[ri * 2];
    lv[s] = mlp[ri * 2 + 1];
    msx = fmaxf(msx, mv[s]);
  }
  f32x4 num = {0.f, 0.f, 0.f, 0.f};
  float L = 0.f;
#pragma unroll
  for (int s = 0; s < 4; ++s) {
    const float wgt = lv[s] * exp2f(mv[s] - msx);
    L += wgt;
    const size_t ri = (size_t)(b * NSPLIT + s) * SEQ + pos;
    const f16x4 ov = *(const f16x4*)&opart[ri * HD + cq];
#pragma unroll
    for (int j = 0; j < 4; ++j) num[j] += wgt * (float)ov[j];
  }
  const float inv = 1.0f / L;
  f32x4 res = {num[0] * inv, num[1] * inv, num[2] * inv, num[3] * inv};
  *(f32x4*)&out[(size_t)row * HD + cq] = res;
}

extern "C" void kernel_launch(void* const* d_in, const int* in_sizes, int n_in,
                              void* d_out, int out_size, void* d_ws, size_t ws_size,
                              hipStream_t stream) {
  const float* query = (const float*)d_in[0];
  const float* key   = (const float*)d_in[1];
  const float* value = (const float*)d_in[2];
  const float* Wq    = (const float*)d_in[3];
  const float* Wk    = (const float*)d_in[4];
  const float* Wv    = (const float*)d_in[5];
  // d_in[6]: causal mask, handled analytically.

  float* out = (float*)d_out;

  _Float16* qh  = (_Float16*)d_ws;
  _Float16* ql  = qh  + (size_t)NB * SEQ * HD;
  _Float16* kh  = ql  + (size_t)NB * SEQ * HD;
  _Float16* kl  = kh  + (size_t)NB * SEQ * HD;
  _Float16* vt  = kl  + (size_t)NB * SEQ * HD;           // [b][64][4096]
  _Float16* opart = vt + (size_t)NB * SEQ * HD;          // [b*4+s][4096][64]
  float* mlp = (float*)(opart + (size_t)NB * NSPLIT * SEQ * HD);

  proj_kernel<<<dim3(256, 3), 256, 0, stream>>>(query, key, value,
                                                Wq, Wk, Wv,
                                                qh, ql, kh, kl, vt);
  attn_kernel<<<dim3(128, NB), 256, 0, stream>>>(qh, ql, kh, kl, vt, opart, mlp);
  combine_kernel<<<1024, 256, 0, stream>>>(opart, mlp, out);
}

// Round 18
// 100.060 us; speedup vs baseline: 1.4593x; 1.4593x over previous
//
#include <hip/hip_runtime.h>
#include <math.h>

// HeadAttention B=4, S=4096, D=1024, DK=DV=64, fp32 in/out, causal.
// Round 18: R15 base + SPLIT-K=2 proj. R17's fp32 revert regressed (104us,
// VALUBusy 51%) -- restored. R15 accounting: per-CU traffic is only 8 B/cy
// (no BW wall) and measured 77us ~= 3x the 24us per-block serial chain --
// co-resident blocks act serialized, and every prior fix changed the
// inside of a block, never its chain LENGTH. Split-K=2 halves the chain:
// 16 steps/block, 1536 blocks (6/CU), f32 partials; X/W traffic unchanged
// (disjoint K-ranges). finish_kernel (R10, verified) sums partials and
// emits qh/ql/kh/kl/vt. attn / combine / wsplit unchanged.

#define SEQ 4096
#define DIM 1024
#define HD  64
#define NB  4
#define NSPLIT 4

typedef __attribute__((ext_vector_type(4))) float    f32x4;
typedef __attribute__((ext_vector_type(8))) _Float16 f16x8;
typedef __attribute__((ext_vector_type(4))) _Float16 f16x4;

#define MFMA16 __builtin_amdgcn_mfma_f32_16x16x32_f16

// swizzled offset into a [row][64] f16 LDS tile (attn): XOR 16B-chunk with row&7
__device__ __forceinline__ int SW(int row, int k) {
  return row * 64 + (k ^ ((row & 7) << 3));
}

// ---------- W pre-split into fragment-linear layout ------------------------
// wf[((which*16+kt)*16 + slot)*512 + lane*8 + j]:
//   slot s=ks*4+ct (0..7) hi-frag, s+8 lo-frag;
//   element = W[k][col]*scale, col=ct*16+(lane&15), k=kt*64+ks*32+(lane>>4)*8+j
__global__ __launch_bounds__(256) void wsplit_kernel(
    const float* __restrict__ Wq, const float* __restrict__ Wk,
    const float* __restrict__ Wv, _Float16* __restrict__ wf)
{
  const int which = blockIdx.x;   // 0..2
  const int kt    = blockIdx.y;   // 0..15
  const float* __restrict__ W = (which == 0) ? Wq : (which == 1) ? Wk : Wv;
  const float scale = (which == 0) ? 0.18033688011112042f : 1.0f;  // log2(e)/8
  const size_t tb = ((size_t)which * 16 + kt) * 8192;
#pragma unroll
  for (int i = 0; i < 2; ++i) {
    const int pair = threadIdx.x + 256 * i;   // 0..511
    const int lane = pair & 63, f = pair >> 6;  // f = ks*4+ct in 0..7
    const int ks = f >> 2, ct = f & 3;
    const int col = ct * 16 + (lane & 15);
    const int k0 = kt * 64 + ks * 32 + (lane >> 4) * 8;
    f16x8 hv, lv;
#pragma unroll
    for (int j = 0; j < 8; ++j) {
      const float y = W[(size_t)(k0 + j) * HD + col] * scale;
      const _Float16 h = (_Float16)y;
      hv[j] = h;
      lv[j] = (_Float16)(y - (float)h);
    }
    *(f16x8*)&wf[tb + (size_t)f * 512 + lane * 8]       = hv;
    *(f16x8*)&wf[tb + (size_t)(8 + f) * 512 + lane * 8] = lv;
  }
}

// ---------- projection: R15 structure, split-K=2, f32 partials -------------
// grid (256, 2, 3), 256 threads (4 waves, 64 output rows). 16 K-steps of
// 32 covering K-range [ksp*512, ksp*512+512). Per step: vmcnt(0) -> 4
// ds_write -> issue next step's 4 loads -> lgkmcnt(0)+s_barrier ->
// ds_reads + 12 MFMA. LDS 32 KB.
__global__ __launch_bounds__(256, 3) void proj_kernel(
    const float* __restrict__ Xq, const float* __restrict__ Xk,
    const float* __restrict__ Xv,
    const _Float16* __restrict__ wf,
    float* __restrict__ Yp)
{
  __shared__ __attribute__((aligned(16))) float    Xs[2][64 * 32];  // 8 KB ea
  __shared__ __attribute__((aligned(16))) _Float16 Ws[2][4096];     // 8 KB ea

  const int ksp   = blockIdx.y;
  const int which = blockIdx.z;
  const float* __restrict__ X = (which == 0) ? Xq : (which == 1) ? Xk : Xv;

  const int t = threadIdx.x, lane = t & 63, w = t >> 6;
  const int bm = blockIdx.x * 64;

  // X: thread t covers row t>>2, 16B chunks c0=(t&3)*2, c0+1; XOR-swizzled.
  const int xrow = t >> 2;
  const int xc   = (t & 3) * 2;
  const float* gX = X + (size_t)(bm + xrow) * DIM + ksp * 512 + xc * 4;
  const int xd0 = xrow * 32 + ((xc ^ (xrow & 7)) * 4);
  const int xd1 = xrow * 32 + (((xc + 1) ^ (xrow & 7)) * 4);

  // W: half-tile hi 4KB + lo 4KB contiguous in wf; thread covers 32B.
  const int wr = t >> 7;
  const int wi = (t & 127) * 16;
  const _Float16* gW = wf + (size_t)which * 131072 + wr * 4096 + wi;
  const int wd = wr * 2048 + wi;

  // read side: lane's A-frag row and k-chunks
  const int frow = lane & 15;
  const int ldsrow = w * 16 + frow;
  const int kc = (lane >> 4) * 2;
  const int xr0 = ldsrow * 32 + ((kc ^ (ldsrow & 7)) * 4);
  const int xr1 = ldsrow * 32 + (((kc + 1) ^ (ldsrow & 7)) * 4);

  f32x4 acc[4] = {{0,0,0,0},{0,0,0,0},{0,0,0,0},{0,0,0,0}};
  f32x4 xg0, xg1;
  f16x8 wg0, wg1;

  auto loadTile = [&](int st) {
    const float* xb = gX + st * 32;
    xg0 = *(const f32x4*)(xb);
    xg1 = *(const f32x4*)(xb + 4);
    const _Float16* wb = gW + (size_t)((st >> 1) + ksp * 8) * 8192
                             + (st & 1) * 2048;
    wg0 = *(const f16x8*)(wb);
    wg1 = *(const f16x8*)(wb + 8);
  };

  loadTile(0);
#pragma unroll 1
  for (int st = 0; st < 16; ++st) {
    const int buf = st & 1;
    asm volatile("s_waitcnt vmcnt(0)" ::: "memory");
    __builtin_amdgcn_sched_barrier(0);
    *(f32x4*)&Xs[buf][xd0] = xg0;
    *(f32x4*)&Xs[buf][xd1] = xg1;
    *(f16x8*)&Ws[buf][wd]     = wg0;
    *(f16x8*)&Ws[buf][wd + 8] = wg1;
    if (st + 1 < 16) loadTile(st + 1);        // flies across the barrier
    asm volatile("s_waitcnt lgkmcnt(0)" ::: "memory");
    __builtin_amdgcn_sched_barrier(0);
    __builtin_amdgcn_s_barrier();
    __builtin_amdgcn_sched_barrier(0);

    // ---- compute this 32-k step
    f32x4 x0 = *(const f32x4*)&Xs[buf][xr0];
    f32x4 x1 = *(const f32x4*)&Xs[buf][xr1];
    f16x8 xh, xl;
#pragma unroll
    for (int j = 0; j < 4; ++j) {
      const _Float16 h0 = (_Float16)x0[j];
      xh[j] = h0; xl[j] = (_Float16)(x0[j] - (float)h0);
      const _Float16 h1 = (_Float16)x1[j];
      xh[j + 4] = h1; xl[j + 4] = (_Float16)(x1[j] - (float)h1);
    }
#pragma unroll
    for (int ct = 0; ct < 4; ++ct) {
      f16x8 bh = *(const f16x8*)&Ws[buf][ct * 512 + lane * 8];
      f16x8 bl = *(const f16x8*)&Ws[buf][2048 + ct * 512 + lane * 8];
      acc[ct] = MFMA16(xh, bh, acc[ct], 0, 0, 0);
      acc[ct] = MFMA16(xl, bh, acc[ct], 0, 0, 0);
      acc[ct] = MFMA16(xh, bl, acc[ct], 0, 0, 0);
    }
  }

  // partial store: C layout col=lane&15, row=(lane>>4)*4+r
  const size_t orow0 = (size_t)bm + w * 16 + (lane >> 4) * 4;
  float* yb = Yp + ((size_t)(ksp * 3 + which) * SEQ * NB) * HD;
#pragma unroll
  for (int ct = 0; ct < 4; ++ct)
#pragma unroll
    for (int r = 0; r < 4; ++r)
      yb[(orow0 + r) * HD + ct * 16 + (lane & 15)] = acc[ct][r];
}

// ---------- finish: sum K-split partials, emit hi/lo splits + vt -----------
// grid (256, 3): block = 64 rows of matrix `which`. which<2 -> row-major
// hi/lo f16; which==2 -> LDS transpose -> vt[b][col][pos].
__global__ __launch_bounds__(256) void finish_kernel(
    const float* __restrict__ Yp,
    _Float16* __restrict__ qh, _Float16* __restrict__ ql,
    _Float16* __restrict__ kh, _Float16* __restrict__ kl,
    _Float16* __restrict__ vt)
{
  __shared__ float Vs[64 * 65];
  const int which = blockIdx.y;
  const int t = threadIdx.x;
  const int row = t >> 2;             // 0..63
  const int c0 = (t & 3) * 16;        // 16-float chunk
  const size_t rbase = (size_t)blockIdx.x * 64;
  const float* y0 = Yp + ((size_t)(0 * 3 + which) * SEQ * NB) * HD;
  const float* y1 = Yp + ((size_t)(1 * 3 + which) * SEQ * NB) * HD;

  float s[16];
#pragma unroll
  for (int u = 0; u < 4; ++u) {
    const size_t off = (rbase + row) * HD + c0 + u * 4;
    f32x4 a = *(const f32x4*)(y0 + off);
    f32x4 b = *(const f32x4*)(y1 + off);
#pragma unroll
    for (int j = 0; j < 4; ++j) s[u * 4 + j] = a[j] + b[j];
  }

  if (which < 2) {
    _Float16* oh = (which == 0) ? qh : kh;
    _Float16* ol = (which == 0) ? ql : kl;
    f16x8 hv0, hv1, lv0, lv1;
#pragma unroll
    for (int j = 0; j < 8; ++j) {
      const _Float16 h0 = (_Float16)s[j];
      hv0[j] = h0; lv0[j] = (_Float16)(s[j] - (float)h0);
      const _Float16 h1 = (_Float16)s[8 + j];
      hv1[j] = h1; lv1[j] = (_Float16)(s[8 + j] - (float)h1);
    }
    const size_t ob = (rbase + row) * HD + c0;
    *(f16x8*)&oh[ob]     = hv0;
    *(f16x8*)&oh[ob + 8] = hv1;
    *(f16x8*)&ol[ob]     = lv0;
    *(f16x8*)&ol[ob + 8] = lv1;
  } else {
#pragma unroll
    for (int j = 0; j < 16; ++j) Vs[row * 65 + c0 + j] = s[j];
    __syncthreads();
    const int col = t >> 2;           // 0..63
    const int p0 = (t & 3) * 16;      // position chunk within the 64 rows
    const int b = (int)(rbase >> 12);
    const int pos = (int)(rbase & 4095) + p0;
    f16x8 o0, o1;
#pragma unroll
    for (int j = 0; j < 8; ++j) {
      o0[j] = (_Float16)Vs[(p0 + j) * 65 + col];
      o1[j] = (_Float16)Vs[(p0 + 8 + j) * 65 + col];
    }
    _Float16* vb = vt + ((size_t)b * HD + col) * SEQ + pos;
    *(f16x8*)(vb)     = o0;
    *(f16x8*)(vb + 8) = o1;
  }
}

// ---------- flash attention, fp16x3 QK + f16 PV, split-4 partials ----------
// grid (128, 4): x -> pair p=x>>2 (q-blocks p and 63-p), parity s=x&3.
__global__ __launch_bounds__(256) void attn_kernel(
    const _Float16* __restrict__ qh, const _Float16* __restrict__ ql,
    const _Float16* __restrict__ kh, const _Float16* __restrict__ kl,
    const _Float16* __restrict__ vt,
    _Float16* __restrict__ opart, float* __restrict__ mlp)
{
  __shared__ __attribute__((aligned(16))) _Float16 Ksh[64 * 64];
  __shared__ __attribute__((aligned(16))) _Float16 Ksl[64 * 64];
  __shared__ __attribute__((aligned(16))) _Float16 Vs [64 * 64];
  __shared__ __attribute__((aligned(16))) _Float16 Pt [64 * 64];

  const int t = threadIdx.x, lane = t & 63, w = t >> 6;
  const int b = blockIdx.y;
  const int p = blockIdx.x >> 2, s = blockIdx.x & 3;
  const size_t bS = (size_t)b * SEQ;

  for (int sel = 0; sel < 2; ++sel) {
    const int qb = sel ? (63 - p) : p;
    const int qrow0 = qb * 64 + w * 16;
    const int nt = (qb >= s) ? ((qb - s) >> 2) + 1 : 0;  // kv tiles ≡ s mod 4

    float m[4] = {-INFINITY, -INFINITY, -INFINITY, -INFINITY};
    float lsum[4] = {0.f, 0.f, 0.f, 0.f};
    f32x4 o[4] = {{0,0,0,0},{0,0,0,0},{0,0,0,0},{0,0,0,0}};

    if (nt > 0) {
      const _Float16* qhp = qh + (bS + qrow0 + (lane & 15)) * HD + ((lane >> 4) * 8);
      const _Float16* qlp = ql + (bS + qrow0 + (lane & 15)) * HD + ((lane >> 4) * 8);
      f16x8 qhf[2], qlf[2];
      qhf[0] = *(const f16x8*)(qhp);      qhf[1] = *(const f16x8*)(qhp + 32);
      qlf[0] = *(const f16x8*)(qlp);      qlf[1] = *(const f16x8*)(qlp + 32);

      for (int i = 0; i < nt; ++i) {
        const int kt = s + 4 * i;
        const int j0 = kt * 64;

        __syncthreads();  // previous tile's LDS reads complete
#pragma unroll
        for (int c = 0; c < 2; ++c) {
          const int lin = t + 256 * c;
          const int row = lin >> 3, d8 = (lin & 7) * 8;
          const int dst = SW(row, d8);
          *(f16x8*)&Ksh[dst] = *(const f16x8*)&kh[(bS + j0 + row) * HD + d8];
          *(f16x8*)&Ksl[dst] = *(const f16x8*)&kl[(bS + j0 + row) * HD + d8];
          *(f16x8*)&Vs[dst]  = *(const f16x8*)&vt[((size_t)b * HD + row) * SEQ + j0 + d8];
        }
        __syncthreads();

        // ---- QK^T: fp16x3
        f32x4 sacc[4] = {{0,0,0,0},{0,0,0,0},{0,0,0,0},{0,0,0,0}};
#pragma unroll
        for (int kk = 0; kk < 2; ++kk)
#pragma unroll
          for (int kt4 = 0; kt4 < 4; ++kt4) {
            const int ba = SW(kt4 * 16 + (lane & 15), kk * 32 + (lane >> 4) * 8);
            f16x8 bh = *(const f16x8*)&Ksh[ba];
            f16x8 bl = *(const f16x8*)&Ksl[ba];
            sacc[kt4] = MFMA16(qhf[kk], bh, sacc[kt4], 0, 0, 0);
            sacc[kt4] = MFMA16(qlf[kk], bh, sacc[kt4], 0, 0, 0);
            sacc[kt4] = MFMA16(qhf[kk], bl, sacc[kt4], 0, 0, 0);
          }

        // ---- causal mask on the diagonal tile
        if (kt == qb) {
#pragma unroll
          for (int kt4 = 0; kt4 < 4; ++kt4) {
            const int key = j0 + kt4 * 16 + (lane & 15);
#pragma unroll
            for (int r = 0; r < 4; ++r)
              if (key > qrow0 + (lane >> 4) * 4 + r) sacc[kt4][r] = -INFINITY;
          }
        }

        // ---- online softmax (exp2 domain), P -> LDS f16
        float alf[4];
#pragma unroll
        for (int r = 0; r < 4; ++r) {
          float mx = fmaxf(fmaxf(sacc[0][r], sacc[1][r]),
                           fmaxf(sacc[2][r], sacc[3][r]));
          mx = fmaxf(mx, __shfl_xor(mx, 1));
          mx = fmaxf(mx, __shfl_xor(mx, 2));
          mx = fmaxf(mx, __shfl_xor(mx, 4));
          mx = fmaxf(mx, __shfl_xor(mx, 8));
          const float mn = fmaxf(m[r], mx);
          const float al = exp2f(m[r] - mn);
          const int prow = w * 16 + (lane >> 4) * 4 + r;
          float ps = 0.f;
#pragma unroll
          for (int kt4 = 0; kt4 < 4; ++kt4) {
            const _Float16 ph = (_Float16)exp2f(sacc[kt4][r] - mn);
            ps += (float)ph;
            Pt[SW(prow, kt4 * 16 + (lane & 15))] = ph;
          }
          ps += __shfl_xor(ps, 1);
          ps += __shfl_xor(ps, 2);
          ps += __shfl_xor(ps, 4);
          ps += __shfl_xor(ps, 8);
          lsum[r] = lsum[r] * al + ps;
          m[r] = mn;
          alf[r] = al;
        }
        const f32x4 av = {alf[0], alf[1], alf[2], alf[3]};
#pragma unroll
        for (int ct = 0; ct < 4; ++ct) o[ct] *= av;

        // ---- PV (per-wave Pt region)
#pragma unroll
        for (int kk = 0; kk < 2; ++kk) {
          f16x8 pa = *(const f16x8*)&Pt[SW(w * 16 + (lane & 15),
                                           kk * 32 + (lane >> 4) * 8)];
#pragma unroll
          for (int ct = 0; ct < 4; ++ct) {
            f16x8 vb = *(const f16x8*)&Vs[SW(ct * 16 + (lane & 15),
                                             kk * 32 + (lane >> 4) * 8)];
            o[ct] = MFMA16(pa, vb, o[ct], 0, 0, 0);
          }
        }
      }
    }

    // ---- write partials: normalized o (f16) + (m, l) f32
    f32x4 invv;
#pragma unroll
    for (int r = 0; r < 4; ++r) invv[r] = (nt > 0) ? 1.0f / lsum[r] : 0.0f;
    const size_t ridx0 = (size_t)(b * NSPLIT + s) * SEQ + qrow0 + (lane >> 4) * 4;
#pragma unroll
    for (int ct = 0; ct < 4; ++ct)
#pragma unroll
      for (int r = 0; r < 4; ++r)
        opart[(ridx0 + r) * HD + ct * 16 + (lane & 15)] =
            (_Float16)(o[ct][r] * invv[r]);
    if ((lane & 15) == 0) {
#pragma unroll
      for (int r = 0; r < 4; ++r) {
        mlp[(ridx0 + r) * 2]     = m[r];
        mlp[(ridx0 + r) * 2 + 1] = lsum[r];
      }
    }
  }
}

// ---------- combine the 4 kv-parity partials -------------------------------
__global__ __launch_bounds__(256) void combine_kernel(
    const _Float16* __restrict__ opart, const float* __restrict__ mlp,
    float* __restrict__ out)
{
  const int g = blockIdx.x * 256 + threadIdx.x;   // 262144
  const int row = g >> 4;
  const int cq = (g & 15) * 4;
  const int b = row >> 12, pos = row & 4095;

  float mv[4], lv[4], msx = -INFINITY;
#pragma unroll
  for (int s = 0; s < 4; ++s) {
    const size_t ri = (size_t)(b * NSPLIT + s) * SEQ + pos;
    mv[s] = mlp[ri * 2];
    lv[s] = mlp[ri * 2 + 1];
    msx = fmaxf(msx, mv[s]);
  }
  f32x4 num = {0.f, 0.f, 0.f, 0.f};
  float L = 0.f;
#pragma unroll
  for (int s = 0; s < 4; ++s) {
    const float wgt = lv[s] * exp2f(mv[s] - msx);
    L += wgt;
    const size_t ri = (size_t)(b * NSPLIT + s) * SEQ + pos;
    const f16x4 ov = *(const f16x4*)&opart[ri * HD + cq];
#pragma unroll
    for (int j = 0; j < 4; ++j) num[j] += wgt * (float)ov[j];
  }
  const float inv = 1.0f / L;
  f32x4 res = {num[0] * inv, num[1] * inv, num[2] * inv, num[3] * inv};
  *(f32x4*)&out[(size_t)row * HD + cq] = res;
}

extern "C" void kernel_launch(void* const* d_in, const int* in_sizes, int n_in,
                              void* d_out, int out_size, void* d_ws, size_t ws_size,
                              hipStream_t stream) {
  const float* query = (const float*)d_in[0];
  const float* key   = (const float*)d_in[1];
  const float* value = (const float*)d_in[2];
  const float* Wq    = (const float*)d_in[3];
  const float* Wk    = (const float*)d_in[4];
  const float* Wv    = (const float*)d_in[5];
  // d_in[6]: causal mask, handled analytically.

  float* out = (float*)d_out;

  _Float16* qh  = (_Float16*)d_ws;
  _Float16* ql  = qh  + (size_t)NB * SEQ * HD;
  _Float16* kh  = ql  + (size_t)NB * SEQ * HD;
  _Float16* kl  = kh  + (size_t)NB * SEQ * HD;
  _Float16* vt  = kl  + (size_t)NB * SEQ * HD;           // [b][64][4096]
  _Float16* wf  = vt  + (size_t)NB * SEQ * HD;           // [3][16][16][512]
  _Float16* opart = wf + (size_t)3 * 16 * 8192;          // [b*4+s][4096][64]
  float* mlp = (float*)(opart + (size_t)NB * NSPLIT * SEQ * HD);
  float* Yp  = mlp + (size_t)NB * NSPLIT * SEQ * 2;      // [2][3][16384][64] f32

  wsplit_kernel<<<dim3(3, 16), 256, 0, stream>>>(Wq, Wk, Wv, wf);
  proj_kernel<<<dim3(256, 2, 3), 256, 0, stream>>>(query, key, value, wf, Yp);
  finish_kernel<<<dim3(256, 3), 256, 0, stream>>>(Yp, qh, ql, kh, kl, vt);
  attn_kernel<<<dim3(128, NB), 256, 0, stream>>>(qh, ql, kh, kl, vt, opart, mlp);
  combine_kernel<<<1024, 256, 0, stream>>>(opart, mlp, out);
}

// Round 19
// 89.578 us; speedup vs baseline: 1.6301x; 1.1170x over previous
//
#include <hip/hip_runtime.h>
#include <math.h>

// HeadAttention B=4, S=4096, D=1024, DK=DV=64, fp32 in/out, causal.
// FINAL (round 19) = round-15 configuration restored verbatim -- the best
// measured total (89.6us, absmax 1.0). Twelve structurally distinct proj
// implementations (staging: LDS-DMA / compiler-reg / asm counted-vmcnt;
// depth 1/2; barriers on/off; occupancy 17-33%; W-traffic 786->98 MB;
// fetch span 256B->1KB; M=64/128; phase stagger; split-K=2; VALU vs MFMA)
// all pin at proj ~77-85us with every pipe <35% busy -- the limiter is
// below this harness's counter observability. Pipeline: proj (fp16x3 MFMA,
// BK=32, LDS-shared W, 3 blocks/CU) -> flash attention (fp16x3 QK + f16
// PV, split-4 kv-parity + paired q-blocks, ~10us) -> combine (~3us).

#define SEQ 4096
#define DIM 1024
#define HD  64
#define NB  4
#define NSPLIT 4

typedef __attribute__((ext_vector_type(4))) float    f32x4;
typedef __attribute__((ext_vector_type(8))) _Float16 f16x8;
typedef __attribute__((ext_vector_type(4))) _Float16 f16x4;

#define MFMA16 __builtin_amdgcn_mfma_f32_16x16x32_f16

// swizzled offset into a [row][64] f16 LDS tile (attn): XOR 16B-chunk with row&7
__device__ __forceinline__ int SW(int row, int k) {
  return row * 64 + (k ^ ((row & 7) << 3));
}

// ---------- W pre-split into fragment-linear layout ------------------------
// wf[((which*16+kt)*16 + slot)*512 + lane*8 + j]:
//   slot s=ks*4+ct (0..7) hi-frag, s+8 lo-frag;
//   element = W[k][col]*scale, col=ct*16+(lane&15), k=kt*64+ks*32+(lane>>4)*8+j
__global__ __launch_bounds__(256) void wsplit_kernel(
    const float* __restrict__ Wq, const float* __restrict__ Wk,
    const float* __restrict__ Wv, _Float16* __restrict__ wf)
{
  const int which = blockIdx.x;   // 0..2
  const int kt    = blockIdx.y;   // 0..15
  const float* __restrict__ W = (which == 0) ? Wq : (which == 1) ? Wk : Wv;
  const float scale = (which == 0) ? 0.18033688011112042f : 1.0f;  // log2(e)/8
  const size_t tb = ((size_t)which * 16 + kt) * 8192;
#pragma unroll
  for (int i = 0; i < 2; ++i) {
    const int pair = threadIdx.x + 256 * i;   // 0..511
    const int lane = pair & 63, f = pair >> 6;  // f = ks*4+ct in 0..7
    const int ks = f >> 2, ct = f & 3;
    const int col = ct * 16 + (lane & 15);
    const int k0 = kt * 64 + ks * 32 + (lane >> 4) * 8;
    f16x8 hv, lv;
#pragma unroll
    for (int j = 0; j < 8; ++j) {
      const float y = W[(size_t)(k0 + j) * HD + col] * scale;
      const _Float16 h = (_Float16)y;
      hv[j] = h;
      lv[j] = (_Float16)(y - (float)h);
    }
    *(f16x8*)&wf[tb + (size_t)f * 512 + lane * 8]       = hv;
    *(f16x8*)&wf[tb + (size_t)(8 + f) * 512 + lane * 8] = lv;
  }
}

// ---------- projection: LDS-shared W, BK=32, 3 resident blocks/CU ----------
// grid (256, 3), 256 threads (4 waves, 64 output rows). 32 K-steps of 32.
// Per step: vmcnt(0) -> 4 ds_write (2 b128 X + 2 b128 W) -> issue next
// step's 4 loads -> lgkmcnt(0)+s_barrier -> 10 ds_read_b128 + 12 MFMA.
// LDS 32 KB -> 5 blocks by LDS, 3 assigned -> all resident (12 waves/CU).
__global__ __launch_bounds__(256, 3) void proj_kernel(
    const float* __restrict__ Xq, const float* __restrict__ Xk,
    const float* __restrict__ Xv,
    const _Float16* __restrict__ wf,
    _Float16* __restrict__ qh, _Float16* __restrict__ ql,
    _Float16* __restrict__ kh, _Float16* __restrict__ kl,
    _Float16* __restrict__ vt)
{
  __shared__ __attribute__((aligned(16))) float    Xs[2][64 * 32];  // 8 KB ea
  __shared__ __attribute__((aligned(16))) _Float16 Ws[2][4096];     // 8 KB ea

  const int which = blockIdx.y;
  const float* __restrict__ X = (which == 0) ? Xq : (which == 1) ? Xk : Xv;

  const int t = threadIdx.x, lane = t & 63, w = t >> 6;
  const int bm = blockIdx.x * 64;

  // X: thread t covers row t>>2 (each wave writes its own 16 rows), 16B
  // chunks c0=(t&3)*2, c0+1 of the 128B row-slice; XOR-swizzled LDS slots.
  const int xrow = t >> 2;
  const int xc   = (t & 3) * 2;
  const float* gX = X + (size_t)(bm + xrow) * DIM + xc * 4;  // +st*32/step
  const int xd0 = xrow * 32 + ((xc ^ (xrow & 7)) * 4);
  const int xd1 = xrow * 32 + (((xc + 1) ^ (xrow & 7)) * 4);

  // W: half-tile = hi 4KB (slots ks*4..+3) + lo 4KB (slots 8+ks*4..+3),
  // both contiguous in wf. Thread covers region r=t>>7 (hi/lo), 32B at
  // (t&127)*16 f16. Waves 0-1 write hi, 2-3 write lo (barrier covers it).
  const int wr = t >> 7;
  const int wi = (t & 127) * 16;
  const _Float16* gW = wf + (size_t)which * 131072 + wr * 4096 + wi;
  const int wd = wr * 2048 + wi;

  // read side: lane's A-frag row and k-chunks
  const int frow = lane & 15;
  const int ldsrow = w * 16 + frow;
  const int kc = (lane >> 4) * 2;
  const int xr0 = ldsrow * 32 + ((kc ^ (ldsrow & 7)) * 4);
  const int xr1 = ldsrow * 32 + (((kc + 1) ^ (ldsrow & 7)) * 4);

  f32x4 acc[4] = {{0,0,0,0},{0,0,0,0},{0,0,0,0},{0,0,0,0}};
  f32x4 xg0, xg1;
  f16x8 wg0, wg1;

  auto loadTile = [&](int st) {
    const float* xb = gX + st * 32;
    xg0 = *(const f32x4*)(xb);
    xg1 = *(const f32x4*)(xb + 4);
    const _Float16* wb = gW + (st >> 1) * 8192 + (st & 1) * 2048;
    wg0 = *(const f16x8*)(wb);
    wg1 = *(const f16x8*)(wb + 8);
  };

  loadTile(0);
#pragma unroll 1
  for (int st = 0; st < 32; ++st) {
    const int buf = st & 1;
    asm volatile("s_waitcnt vmcnt(0)" ::: "memory");
    __builtin_amdgcn_sched_barrier(0);
    *(f32x4*)&Xs[buf][xd0] = xg0;
    *(f32x4*)&Xs[buf][xd1] = xg1;
    *(f16x8*)&Ws[buf][wd]     = wg0;
    *(f16x8*)&Ws[buf][wd + 8] = wg1;
    if (st + 1 < 32) loadTile(st + 1);        // flies across the barrier
    asm volatile("s_waitcnt lgkmcnt(0)" ::: "memory");
    __builtin_amdgcn_sched_barrier(0);
    __builtin_amdgcn_s_barrier();
    __builtin_amdgcn_sched_barrier(0);

    // ---- compute this 32-k step
    f32x4 x0 = *(const f32x4*)&Xs[buf][xr0];
    f32x4 x1 = *(const f32x4*)&Xs[buf][xr1];
    f16x8 xh, xl;
#pragma unroll
    for (int j = 0; j < 4; ++j) {
      const _Float16 h0 = (_Float16)x0[j];
      xh[j] = h0; xl[j] = (_Float16)(x0[j] - (float)h0);
      const _Float16 h1 = (_Float16)x1[j];
      xh[j + 4] = h1; xl[j + 4] = (_Float16)(x1[j] - (float)h1);
    }
#pragma unroll
    for (int ct = 0; ct < 4; ++ct) {
      f16x8 bh = *(const f16x8*)&Ws[buf][ct * 512 + lane * 8];
      f16x8 bl = *(const f16x8*)&Ws[buf][2048 + ct * 512 + lane * 8];
      acc[ct] = MFMA16(xh, bh, acc[ct], 0, 0, 0);
      acc[ct] = MFMA16(xl, bh, acc[ct], 0, 0, 0);
      acc[ct] = MFMA16(xh, bl, acc[ct], 0, 0, 0);
    }
  }

  // epilogue: C layout col=lane&15, row=(lane>>4)*4+r
  const size_t orow0 = (size_t)bm + w * 16 + (lane >> 4) * 4;
  if (which < 2) {
    _Float16* oh = (which == 0) ? qh : kh;
    _Float16* ol = (which == 0) ? ql : kl;
#pragma unroll
    for (int ct = 0; ct < 4; ++ct)
#pragma unroll
      for (int r = 0; r < 4; ++r) {
        const float y = acc[ct][r];
        const _Float16 h = (_Float16)y;
        const size_t idx = (orow0 + r) * HD + ct * 16 + (lane & 15);
        oh[idx] = h;
        ol[idx] = (_Float16)(y - (float)h);
      }
  } else {
    const int batch = (int)(orow0 >> 12);
    const int pos = (int)(orow0 & 4095);
#pragma unroll
    for (int ct = 0; ct < 4; ++ct) {
      f16x4 hv;
#pragma unroll
      for (int r = 0; r < 4; ++r) hv[r] = (_Float16)acc[ct][r];
      *(f16x4*)&vt[((size_t)batch * HD + ct * 16 + (lane & 15)) * SEQ + pos] = hv;
    }
  }
}

// ---------- flash attention, fp16x3 QK + f16 PV, split-4 partials ----------
// grid (128, 4): x -> pair p=x>>2 (q-blocks p and 63-p), parity s=x&3.
__global__ __launch_bounds__(256) void attn_kernel(
    const _Float16* __restrict__ qh, const _Float16* __restrict__ ql,
    const _Float16* __restrict__ kh, const _Float16* __restrict__ kl,
    const _Float16* __restrict__ vt,
    _Float16* __restrict__ opart, float* __restrict__ mlp)
{
  __shared__ __attribute__((aligned(16))) _Float16 Ksh[64 * 64];
  __shared__ __attribute__((aligned(16))) _Float16 Ksl[64 * 64];
  __shared__ __attribute__((aligned(16))) _Float16 Vs [64 * 64];
  __shared__ __attribute__((aligned(16))) _Float16 Pt [64 * 64];

  const int t = threadIdx.x, lane = t & 63, w = t >> 6;
  const int b = blockIdx.y;
  const int p = blockIdx.x >> 2, s = blockIdx.x & 3;
  const size_t bS = (size_t)b * SEQ;

  for (int sel = 0; sel < 2; ++sel) {
    const int qb = sel ? (63 - p) : p;
    const int qrow0 = qb * 64 + w * 16;
    const int nt = (qb >= s) ? ((qb - s) >> 2) + 1 : 0;  // kv tiles ≡ s mod 4

    float m[4] = {-INFINITY, -INFINITY, -INFINITY, -INFINITY};
    float lsum[4] = {0.f, 0.f, 0.f, 0.f};
    f32x4 o[4] = {{0,0,0,0},{0,0,0,0},{0,0,0,0},{0,0,0,0}};

    if (nt > 0) {
      const _Float16* qhp = qh + (bS + qrow0 + (lane & 15)) * HD + ((lane >> 4) * 8);
      const _Float16* qlp = ql + (bS + qrow0 + (lane & 15)) * HD + ((lane >> 4) * 8);
      f16x8 qhf[2], qlf[2];
      qhf[0] = *(const f16x8*)(qhp);      qhf[1] = *(const f16x8*)(qhp + 32);
      qlf[0] = *(const f16x8*)(qlp);      qlf[1] = *(const f16x8*)(qlp + 32);

      for (int i = 0; i < nt; ++i) {
        const int kt = s + 4 * i;
        const int j0 = kt * 64;

        __syncthreads();  // previous tile's LDS reads complete
#pragma unroll
        for (int c = 0; c < 2; ++c) {
          const int lin = t + 256 * c;
          const int row = lin >> 3, d8 = (lin & 7) * 8;
          const int dst = SW(row, d8);
          *(f16x8*)&Ksh[dst] = *(const f16x8*)&kh[(bS + j0 + row) * HD + d8];
          *(f16x8*)&Ksl[dst] = *(const f16x8*)&kl[(bS + j0 + row) * HD + d8];
          *(f16x8*)&Vs[dst]  = *(const f16x8*)&vt[((size_t)b * HD + row) * SEQ + j0 + d8];
        }
        __syncthreads();

        // ---- QK^T: fp16x3
        f32x4 sacc[4] = {{0,0,0,0},{0,0,0,0},{0,0,0,0},{0,0,0,0}};
#pragma unroll
        for (int kk = 0; kk < 2; ++kk)
#pragma unroll
          for (int kt4 = 0; kt4 < 4; ++kt4) {
            const int ba = SW(kt4 * 16 + (lane & 15), kk * 32 + (lane >> 4) * 8);
            f16x8 bh = *(const f16x8*)&Ksh[ba];
            f16x8 bl = *(const f16x8*)&Ksl[ba];
            sacc[kt4] = MFMA16(qhf[kk], bh, sacc[kt4], 0, 0, 0);
            sacc[kt4] = MFMA16(qlf[kk], bh, sacc[kt4], 0, 0, 0);
            sacc[kt4] = MFMA16(qhf[kk], bl, sacc[kt4], 0, 0, 0);
          }

        // ---- causal mask on the diagonal tile
        if (kt == qb) {
#pragma unroll
          for (int kt4 = 0; kt4 < 4; ++kt4) {
            const int key = j0 + kt4 * 16 + (lane & 15);
#pragma unroll
            for (int r = 0; r < 4; ++r)
              if (key > qrow0 + (lane >> 4) * 4 + r) sacc[kt4][r] = -INFINITY;
          }
        }

        // ---- online softmax (exp2 domain), P -> LDS f16
        float alf[4];
#pragma unroll
        for (int r = 0; r < 4; ++r) {
          float mx = fmaxf(fmaxf(sacc[0][r], sacc[1][r]),
                           fmaxf(sacc[2][r], sacc[3][r]));
          mx = fmaxf(mx, __shfl_xor(mx, 1));
          mx = fmaxf(mx, __shfl_xor(mx, 2));
          mx = fmaxf(mx, __shfl_xor(mx, 4));
          mx = fmaxf(mx, __shfl_xor(mx, 8));
          const float mn = fmaxf(m[r], mx);
          const float al = exp2f(m[r] - mn);
          const int prow = w * 16 + (lane >> 4) * 4 + r;
          float ps = 0.f;
#pragma unroll
          for (int kt4 = 0; kt4 < 4; ++kt4) {
            const _Float16 ph = (_Float16)exp2f(sacc[kt4][r] - mn);
            ps += (float)ph;
            Pt[SW(prow, kt4 * 16 + (lane & 15))] = ph;
          }
          ps += __shfl_xor(ps, 1);
          ps += __shfl_xor(ps, 2);
          ps += __shfl_xor(ps, 4);
          ps += __shfl_xor(ps, 8);
          lsum[r] = lsum[r] * al + ps;
          m[r] = mn;
          alf[r] = al;
        }
        const f32x4 av = {alf[0], alf[1], alf[2], alf[3]};
#pragma unroll
        for (int ct = 0; ct < 4; ++ct) o[ct] *= av;

        // ---- PV (per-wave Pt region)
#pragma unroll
        for (int kk = 0; kk < 2; ++kk) {
          f16x8 pa = *(const f16x8*)&Pt[SW(w * 16 + (lane & 15),
                                           kk * 32 + (lane >> 4) * 8)];
#pragma unroll
          for (int ct = 0; ct < 4; ++ct) {
            f16x8 vb = *(const f16x8*)&Vs[SW(ct * 16 + (lane & 15),
                                             kk * 32 + (lane >> 4) * 8)];
            o[ct] = MFMA16(pa, vb, o[ct], 0, 0, 0);
          }
        }
      }
    }

    // ---- write partials: normalized o (f16) + (m, l) f32
    f32x4 invv;
#pragma unroll
    for (int r = 0; r < 4; ++r) invv[r] = (nt > 0) ? 1.0f / lsum[r] : 0.0f;
    const size_t ridx0 = (size_t)(b * NSPLIT + s) * SEQ + qrow0 + (lane >> 4) * 4;
#pragma unroll
    for (int ct = 0; ct < 4; ++ct)
#pragma unroll
      for (int r = 0; r < 4; ++r)
        opart[(ridx0 + r) * HD + ct * 16 + (lane & 15)] =
            (_Float16)(o[ct][r] * invv[r]);
    if ((lane & 15) == 0) {
#pragma unroll
      for (int r = 0; r < 4; ++r) {
        mlp[(ridx0 + r) * 2]     = m[r];
        mlp[(ridx0 + r) * 2 + 1] = lsum[r];
      }
    }
  }
}

// ---------- combine the 4 kv-parity partials -------------------------------
__global__ __launch_bounds__(256) void combine_kernel(
    const _Float16* __restrict__ opart, const float* __restrict__ mlp,
    float* __restrict__ out)
{
  const int g = blockIdx.x * 256 + threadIdx.x;   // 262144
  const int row = g >> 4;
  const int cq = (g & 15) * 4;
  const int b = row >> 12, pos = row & 4095;

  float mv[4], lv[4], msx = -INFINITY;
#pragma unroll
  for (int s = 0; s < 4; ++s) {
    const size_t ri = (size_t)(b * NSPLIT + s) * SEQ + pos;
    mv[s] = mlp[ri * 2];
    lv[s] = mlp[ri * 2 + 1];
    msx = fmaxf(msx, mv[s]);
  }
  f32x4 num = {0.f, 0.f, 0.f, 0.f};
  float L = 0.f;
#pragma unroll
  for (int s = 0; s < 4; ++s) {
    const float wgt = lv[s] * exp2f(mv[s] - msx);
    L += wgt;
    const size_t ri = (size_t)(b * NSPLIT + s) * SEQ + pos;
    const f16x4 ov = *(const f16x4*)&opart[ri * HD + cq];
#pragma unroll
    for (int j = 0; j < 4; ++j) num[j] += wgt * (float)ov[j];
  }
  const float inv = 1.0f / L;
  f32x4 res = {num[0] * inv, num[1] * inv, num[2] * inv, num[3] * inv};
  *(f32x4*)&out[(size_t)row * HD + cq] = res;
}

extern "C" void kernel_launch(void* const* d_in, const int* in_sizes, int n_in,
                              void* d_out, int out_size, void* d_ws, size_t ws_size,
                              hipStream_t stream) {
  const float* query = (const float*)d_in[0];
  const float* key   = (const float*)d_in[1];
  const float* value = (const float*)d_in[2];
  const float* Wq    = (const float*)d_in[3];
  const float* Wk    = (const float*)d_in[4];
  const float* Wv    = (const float*)d_in[5];
  // d_in[6]: causal mask, handled analytically.

  float* out = (float*)d_out;

  _Float16* qh  = (_Float16*)d_ws;
  _Float16* ql  = qh  + (size_t)NB * SEQ * HD;
  _Float16* kh  = ql  + (size_t)NB * SEQ * HD;
  _Float16* kl  = kh  + (size_t)NB * SEQ * HD;
  _Float16* vt  = kl  + (size_t)NB * SEQ * HD;           // [b][64][4096]
  _Float16* wf  = vt  + (size_t)NB * SEQ * HD;           // [3][16][16][512]
  _Float16* opart = wf + (size_t)3 * 16 * 8192;          // [b*4+s][4096][64]
  float* mlp = (float*)(opart + (size_t)NB * NSPLIT * SEQ * HD);

  wsplit_kernel<<<dim3(3, 16), 256, 0, stream>>>(Wq, Wk, Wv, wf);
  proj_kernel<<<dim3(256, 3), 256, 0, stream>>>(query, key, value, wf,
                                                qh, ql, kh, kl, vt);
  attn_kernel<<<dim3(128, NB), 256, 0, stream>>>(qh, ql, kh, kl, vt, opart, mlp);
  combine_kernel<<<1024, 256, 0, stream>>>(opart, mlp, out);
}